// Round 2
// baseline (1213.049 us; speedup 1.0000x reference)
//
#include <hip/hip_runtime.h>
#include <hip/hip_bf16.h>
#include <stdint.h>

#define M_ROWS 300000

typedef __attribute__((ext_vector_type(8)))  short bf16x8;
typedef __attribute__((ext_vector_type(16))) float f32x16;

union U4 { uint4 u; bf16x8 h; unsigned short us[8]; };

__device__ __forceinline__ unsigned short f2bf(float f) {
  union { float f; uint32_t u; } v; v.f = f;
  uint32_t r = v.u + 0x7fffu + ((v.u >> 16) & 1u);
  return (unsigned short)(r >> 16);
}

// ---- packed weight tile table (tiles of 32 cols x 16 k, 1 KiB each) ----
#define T_SP 0
#define T_ST 64
#define T_P1 128
#define T_P2 256
#define T_R1 272
#define T_R2 400
#define T_S1 416
#define T_S2 544
#define T_W1 576
#define T_W2 704
#define T_M1 720
#define T_M2 848
#define T_TOT 864

__global__ void prep_w(const float* Wsp, const float* Wst, const float* Wp1, const float* Wp2,
                       const float* Wr1, const float* Wr2, const float* Ws1, const float* Ws2,
                       const float* Ww1, const float* Ww2, const float* Wm1, const float* Wm2,
                       uint4* ws) {
  int b = blockIdx.x, l = threadIdx.x;
  const int starts[12] = {T_SP,T_ST,T_P1,T_P2,T_R1,T_R2,T_S1,T_S2,T_W1,T_W2,T_M1,T_M2};
  const int Ks[12]     = {128,128,256,256,256,256,256,256,256,256,256,256};
  const int Cos[12]    = {256,256,256,9,256,4,256,48,256,1,256,1};
  const float* Wp[12]  = {Wsp,Wst,Wp1,Wp2,Wr1,Wr2,Ws1,Ws2,Ww1,Ww2,Wm1,Wm2};
  int m = 0;
  #pragma unroll
  for (int i = 1; i < 12; ++i) if (b >= starts[i]) m = i;
  int local = b - starts[m];
  int KT = Ks[m] >> 4;
  int n0 = local / KT, k0 = local - n0 * KT;
  int col = n0 * 32 + (l & 31);
  int kbase = k0 * 16 + (l >> 5) * 8;
  const float* W = Wp[m];
  int Co = Cos[m];
  U4 pk;
  #pragma unroll
  for (int j = 0; j < 8; ++j) {
    float v = (col < Co) ? W[(size_t)(kbase + j) * Co + col] : 0.0f;
    pk.us[j] = f2bf(v);
  }
  ws[(size_t)b * 64 + l] = pk.u;
}

// ---- bulk copy of embeddings into output (non-indexed rows) ----
__global__ void copy_emb(const float4* pts, const float4* rot, const float4* h,
                         const float4* shs, float4* out) {
  long long stride = (long long)gridDim.x * blockDim.x;
  for (long long i = (long long)blockIdx.x * blockDim.x + threadIdx.x; i < 8400000LL; i += stride) {
    float4 v;
    if (i < 450000)        v = pts[i];
    else if (i < 1050000)  v = rot[i - 450000];
    else if (i < 1200000)  v = h[i - 1050000];
    else                   v = shs[i - 1200000];
    out[i] = v;
  }
}

// ---- fused MLP kernel: 128 rows/block, 4 waves, col-split ----
#define LSTR 512
__device__ __forceinline__ int lds_addr(int row, int cb) {
  return row * LSTR + (cb ^ ((row & 15) << 4));
}

__device__ __forceinline__ void loadX(const float* grid, int row0, int t, char* buf) {
  #pragma unroll
  for (int i = 0; i < 16; ++i) {
    int fi = i * 256 + t;
    int row = fi >> 5;
    int c4 = fi & 31;
    int gr = row0 + row; gr = gr < M_ROWS ? gr : (M_ROWS - 1);
    float4 v = ((const float4*)grid)[(size_t)gr * 32 + c4];
    ushort4 p;
    p.x = f2bf(v.x); p.y = f2bf(v.y); p.z = f2bf(v.z); p.w = f2bf(v.w);
    *(ushort4*)(buf + lds_addr(row, c4 * 8)) = p;
  }
}

// Big layer: wave owns cols [wave*64, wave*64+64), all 128 rows.
// B slice (2*KT tiles) batch-prefetched into registers up front.
template<int KT>
__device__ __forceinline__ void big_layer(const uint4* wt, const float* bias,
                                          const char* inb, char* outb,
                                          int wave, int lane) {
  U4 b[2][KT];
  #pragma unroll
  for (int n = 0; n < 2; ++n)
    #pragma unroll
    for (int k = 0; k < KT; ++k)
      b[n][k].u = wt[(size_t)(((wave * 2 + n) * KT + k) * 64 + lane)];
  f32x16 acc[4][2];
  #pragma unroll
  for (int r = 0; r < 4; ++r) { acc[r][0] = (f32x16)0.0f; acc[r][1] = (f32x16)0.0f; }
  const int arow0 = lane & 31;
  const int khalf = (lane >> 5) * 16;
  #pragma unroll
  for (int k = 0; k < KT; ++k) {
    bf16x8 a[4];
    #pragma unroll
    for (int r = 0; r < 4; ++r)
      a[r] = *(const bf16x8*)(inb + lds_addr(r * 32 + arow0, k * 32 + khalf));
    #pragma unroll
    for (int r = 0; r < 4; ++r) {
      acc[r][0] = __builtin_amdgcn_mfma_f32_32x32x16_bf16(a[r], b[0][k].h, acc[r][0], 0, 0, 0);
      acc[r][1] = __builtin_amdgcn_mfma_f32_32x32x16_bf16(a[r], b[1][k].h, acc[r][1], 0, 0, 0);
    }
  }
  #pragma unroll
  for (int n = 0; n < 2; ++n) {
    int col = (wave * 2 + n) * 32 + (lane & 31);
    float bv = bias[col];
    #pragma unroll
    for (int r = 0; r < 4; ++r)
      #pragma unroll
      for (int q = 0; q < 16; ++q) {
        int row = r * 32 + (q & 3) + 8 * (q >> 2) + 4 * (lane >> 5);
        float v = acc[r][n][q] + bv;
        v = v > 0.0f ? v : 0.0f;
        *(unsigned short*)(outb + lds_addr(row, col * 2)) = f2bf(v);
      }
  }
}

// Small head: wave owns row-tile [wave*32, wave*32+32), full K=256, NT col-tiles.
template<int NT>
__device__ __forceinline__ void head_mm(const uint4* wt, const char* inb,
                                        int wave, int lane, f32x16 (&acc)[NT]) {
  U4 b[NT][16];
  #pragma unroll
  for (int n = 0; n < NT; ++n)
    #pragma unroll
    for (int k = 0; k < 16; ++k)
      b[n][k].u = wt[(size_t)((n * 16 + k) * 64 + lane)];
  #pragma unroll
  for (int n = 0; n < NT; ++n) acc[n] = (f32x16)0.0f;
  const int arow0 = lane & 31;
  const int khalf = (lane >> 5) * 16;
  const int rbase = wave * 32;
  #pragma unroll
  for (int k = 0; k < 16; ++k) {
    bf16x8 a = *(const bf16x8*)(inb + lds_addr(rbase + arow0, k * 32 + khalf));
    #pragma unroll
    for (int n = 0; n < NT; ++n)
      acc[n] = __builtin_amdgcn_mfma_f32_32x32x16_bf16(a, b[n][k].h, acc[n], 0, 0, 0);
  }
}

__global__ void __launch_bounds__(256, 1) deform_main(
    const float* grid_sp, const float* grid_st, const int* idx,
    const float* rays, const float* rotq, const float* shs_in,
    const float* time_emb, const float* h_emb,
    const uint4* ws,
    const float* b_sp, const float* b_st, const float* b_p1, const float* b_p2,
    const float* b_r1, const float* b_r2, const float* b_s1, const float* b_s2,
    const float* b_w1, const float* b_w2, const float* b_m1, const float* b_m2,
    float* out) {
  __shared__ char bufA[65536];
  __shared__ char bufB[65536];
  __shared__ float wbuf[128];

  const int t = threadIdx.x;
  const int lane = t & 63;
  const int wave = t >> 6;
  const int row0 = blockIdx.x * 128;
  const float tt = time_emb[0];

  // ---- sp trunk ----
  loadX(grid_sp, row0, t, bufA);
  __syncthreads();
  big_layer<8>(ws + T_SP * 64, b_sp, bufA, bufB, wave, lane);   // hsp -> bufB
  __syncthreads();
  big_layer<16>(ws + T_P1 * 64, b_p1, bufB, bufA, wave, lane);  // hp -> bufA
  __syncthreads();
  { // dx head + pts epilogue (direct from regs)
    f32x16 acc[1];
    head_mm<1>(ws + T_P2 * 64, bufA, wave, lane, acc);
    const int col = lane & 31;
    const float mt = 1.0f - tt;
    const float c0 = 3.0f * mt * mt * tt, c1 = 3.0f * mt * tt * tt, c2 = tt * tt * tt;
    const float bb = (col < 9) ? b_p2[col] : 0.0f;
    #pragma unroll
    for (int q = 0; q < 16; ++q) {
      int row = (q & 3) + 8 * (q >> 2) + 4 * (lane >> 5);
      int gr = row0 + wave * 32 + row;
      float v = acc[0][q] + bb;
      float d1 = __shfl(v, lane + 3, 64);
      float d2 = __shfl(v, lane + 6, 64);
      if (col < 3 && gr < M_ROWS) {
        int g = idx[gr];
        out[(size_t)g * 3 + col] = rays[(size_t)g * 3 + col] + (c0 * v + c1 * d1 + c2 * d2);
      }
    }
  }
  __syncthreads();
  big_layer<16>(ws + T_W1 * 64, b_w1, bufB, bufA, wave, lane);  // hw -> bufA
  __syncthreads();
  { // w head -> wbuf
    f32x16 acc[1];
    head_mm<1>(ws + T_W2 * 64, bufA, wave, lane, acc);
    if ((lane & 31) == 0) {
      #pragma unroll
      for (int q = 0; q < 16; ++q) {
        int row = (q & 3) + 8 * (q >> 2) + 4 * (lane >> 5);
        wbuf[wave * 32 + row] = acc[0][q] + b_w2[0];
      }
    }
  }
  __syncthreads();
  big_layer<16>(ws + T_M1 * 64, b_m1, bufB, bufA, wave, lane);  // hm -> bufA
  __syncthreads();
  { // mu head + opacity epilogue
    f32x16 acc[1];
    head_mm<1>(ws + T_M2 * 64, bufA, wave, lane, acc);
    if ((lane & 31) == 0) {
      #pragma unroll
      for (int q = 0; q < 16; ++q) {
        int row = (q & 3) + 8 * (q >> 2) + 4 * (lane >> 5);
        int gr = row0 + wave * 32 + row;
        if (gr < M_ROWS) {
          int g = idx[gr];
          float mu = 1.0f / (1.0f + expf(-(acc[0][q] + b_m2[0])));
          float w = wbuf[wave * 32 + row];
          float d = tt - mu;
          out[4200000 + (size_t)g] = h_emb[g] * expf(-(w * w) * d * d);
        }
      }
    }
  }
  __syncthreads();

  // ---- st trunk ----
  loadX(grid_st, row0, t, bufA);
  __syncthreads();
  big_layer<8>(ws + T_ST * 64, b_st, bufA, bufB, wave, lane);   // hst -> bufB
  __syncthreads();
  big_layer<16>(ws + T_R1 * 64, b_r1, bufB, bufA, wave, lane);  // hr -> bufA
  __syncthreads();
  { // rot head (direct write)
    f32x16 acc[1];
    head_mm<1>(ws + T_R2 * 64, bufA, wave, lane, acc);
    const int col = lane & 31;
    if (col < 4) {
      const float bb = b_r2[col];
      #pragma unroll
      for (int q = 0; q < 16; ++q) {
        int row = (q & 3) + 8 * (q >> 2) + 4 * (lane >> 5);
        int gr = row0 + wave * 32 + row;
        if (gr < M_ROWS) {
          int g = idx[gr];
          out[1800000 + (size_t)g * 4 + col] = rotq[(size_t)g * 4 + col] + acc[0][q] + bb;
        }
      }
    }
  }
  __syncthreads();
  big_layer<16>(ws + T_S1 * 64, b_s1, bufB, bufA, wave, lane);  // hs -> bufA
  __syncthreads();
  { // shs head (direct write)
    f32x16 acc[2];
    head_mm<2>(ws + T_S2 * 64, bufA, wave, lane, acc);
    #pragma unroll
    for (int n = 0; n < 2; ++n) {
      int col = n * 32 + (lane & 31);
      if (col < 48) {
        float bb = b_s2[col];
        #pragma unroll
        for (int q = 0; q < 16; ++q) {
          int row = (q & 3) + 8 * (q >> 2) + 4 * (lane >> 5);
          int gr = row0 + wave * 32 + row;
          if (gr < M_ROWS) {
            int g = idx[gr];
            out[4800000 + (size_t)g * 48 + col] = shs_in[(size_t)g * 48 + col] + acc[n][q] + bb;
          }
        }
      }
    }
  }
}

extern "C" void kernel_launch(void* const* d_in, const int* in_sizes, int n_in,
                              void* d_out, int out_size, void* d_ws, size_t ws_size,
                              hipStream_t stream) {
  const float* rays     = (const float*)d_in[0];
  const float* rotq     = (const float*)d_in[1];
  const float* shs      = (const float*)d_in[2];
  const float* time_emb = (const float*)d_in[3];
  const float* h_emb    = (const float*)d_in[4];
  const float* grid_sp  = (const float*)d_in[5];
  const float* grid_st  = (const float*)d_in[6];
  const int*   idx      = (const int*)d_in[7];
  uint4* ws = (uint4*)d_ws;

  prep_w<<<T_TOT, 64, 0, stream>>>(
      (const float*)d_in[8],  (const float*)d_in[10], (const float*)d_in[12], (const float*)d_in[14],
      (const float*)d_in[16], (const float*)d_in[18], (const float*)d_in[20], (const float*)d_in[22],
      (const float*)d_in[24], (const float*)d_in[26], (const float*)d_in[28], (const float*)d_in[30],
      ws);

  copy_emb<<<2048, 256, 0, stream>>>((const float4*)rays, (const float4*)rotq,
                                     (const float4*)h_emb, (const float4*)shs, (float4*)d_out);

  deform_main<<<(M_ROWS + 127) / 128, 256, 0, stream>>>(
      grid_sp, grid_st, idx, rays, rotq, shs, time_emb, h_emb, ws,
      (const float*)d_in[9],  (const float*)d_in[11], (const float*)d_in[13], (const float*)d_in[15],
      (const float*)d_in[17], (const float*)d_in[19], (const float*)d_in[21], (const float*)d_in[23],
      (const float*)d_in[25], (const float*)d_in[27], (const float*)d_in[29], (const float*)d_in[31],
      (float*)d_out);
}

// Round 3
// 945.919 us; speedup vs baseline: 1.2824x; 1.2824x over previous
//
#include <hip/hip_runtime.h>
#include <hip/hip_bf16.h>
#include <stdint.h>

#define M_ROWS 300000

typedef __attribute__((ext_vector_type(8)))  short bf16x8;
typedef __attribute__((ext_vector_type(16))) float f32x16;

union U4 { uint4 u; bf16x8 h; unsigned short us[8]; };

__device__ __forceinline__ unsigned short f2bf(float f) {
  union { float f; uint32_t u; } v; v.f = f;
  uint32_t r = v.u + 0x7fffu + ((v.u >> 16) & 1u);
  return (unsigned short)(r >> 16);
}

// ---- packed weight tile table (tiles of 32 cols x 16 k, 1 KiB each) ----
#define T_SP 0
#define T_ST 64
#define T_P1 128
#define T_P2 256
#define T_R1 272
#define T_R2 400
#define T_S1 416
#define T_S2 544
#define T_W1 576
#define T_W2 704
#define T_M1 720
#define T_M2 848
#define T_TOT 864

__global__ void prep_w(const float* Wsp, const float* Wst, const float* Wp1, const float* Wp2,
                       const float* Wr1, const float* Wr2, const float* Ws1, const float* Ws2,
                       const float* Ww1, const float* Ww2, const float* Wm1, const float* Wm2,
                       uint4* ws) {
  int b = blockIdx.x, l = threadIdx.x;
  const int starts[12] = {T_SP,T_ST,T_P1,T_P2,T_R1,T_R2,T_S1,T_S2,T_W1,T_W2,T_M1,T_M2};
  const int Ks[12]     = {128,128,256,256,256,256,256,256,256,256,256,256};
  const int Cos[12]    = {256,256,256,9,256,4,256,48,256,1,256,1};
  const float* Wp[12]  = {Wsp,Wst,Wp1,Wp2,Wr1,Wr2,Ws1,Ws2,Ww1,Ww2,Wm1,Wm2};
  int m = 0;
  #pragma unroll
  for (int i = 1; i < 12; ++i) if (b >= starts[i]) m = i;
  int local = b - starts[m];
  int KT = Ks[m] >> 4;
  int n0 = local / KT, k0 = local - n0 * KT;
  int col = n0 * 32 + (l & 31);
  int kbase = k0 * 16 + (l >> 5) * 8;
  const float* W = Wp[m];
  int Co = Cos[m];
  U4 pk;
  #pragma unroll
  for (int j = 0; j < 8; ++j) {
    float v = (col < Co) ? W[(size_t)(kbase + j) * Co + col] : 0.0f;
    pk.us[j] = f2bf(v);
  }
  ws[(size_t)b * 64 + l] = pk.u;
}

// ---- bulk copy of embeddings into output (non-indexed rows) ----
__global__ void copy_emb(const float4* pts, const float4* rot, const float4* h,
                         const float4* shs, float4* out) {
  long long stride = (long long)gridDim.x * blockDim.x;
  for (long long i = (long long)blockIdx.x * blockDim.x + threadIdx.x; i < 8400000LL; i += stride) {
    float4 v;
    if (i < 450000)        v = pts[i];
    else if (i < 1050000)  v = rot[i - 450000];
    else if (i < 1200000)  v = h[i - 1050000];
    else                   v = shs[i - 1200000];
    out[i] = v;
  }
}

// ---- fused MLP kernel: 64 rows/block, 8 waves ----
#define LSTR 512
__device__ __forceinline__ int lds_addr(int row, int cb) {
  return row * LSTR + (cb ^ ((row & 15) << 4));
}

__device__ __forceinline__ void loadX(const float* grid, int row0, int t, char* buf) {
  #pragma unroll
  for (int i = 0; i < 4; ++i) {
    int fi = i * 512 + t;
    int row = fi >> 5;
    int c4 = fi & 31;
    int gr = row0 + row; gr = gr < M_ROWS ? gr : (M_ROWS - 1);
    float4 v = ((const float4*)grid)[(size_t)gr * 32 + c4];
    ushort4 p;
    p.x = f2bf(v.x); p.y = f2bf(v.y); p.z = f2bf(v.z); p.w = f2bf(v.w);
    *(ushort4*)(buf + lds_addr(row, c4 * 8)) = p;
  }
}

// Big layer: wave owns cols [wave*32, wave*32+32), 64 rows.
// B tiles ring-prefetched (depth 3) to hide L2 latency under the k-loop.
template<int KT>
__device__ __forceinline__ void big_layer(const uint4* wt, const float* bias,
                                          const char* inb, char* outb,
                                          int wave, int lane) {
  const uint4* wb = wt + (size_t)wave * KT * 64 + lane;
  U4 b[4];
  b[0].u = wb[0]; b[1].u = wb[64]; b[2].u = wb[128];
  f32x16 acc0 = (f32x16)0.0f, acc1 = (f32x16)0.0f;
  const int arow = lane & 31;
  const int khalf = (lane >> 5) * 16;
  #pragma unroll
  for (int k = 0; k < KT; ++k) {
    if (k + 3 < KT) b[(k + 3) & 3].u = wb[(size_t)(k + 3) * 64];
    bf16x8 a0 = *(const bf16x8*)(inb + lds_addr(arow, k * 32 + khalf));
    bf16x8 a1 = *(const bf16x8*)(inb + lds_addr(32 + arow, k * 32 + khalf));
    acc0 = __builtin_amdgcn_mfma_f32_32x32x16_bf16(a0, b[k & 3].h, acc0, 0, 0, 0);
    acc1 = __builtin_amdgcn_mfma_f32_32x32x16_bf16(a1, b[k & 3].h, acc1, 0, 0, 0);
  }
  const int col = wave * 32 + (lane & 31);
  const float bv = bias[col];
  #pragma unroll
  for (int q = 0; q < 16; ++q) {
    int row = (q & 3) + 8 * (q >> 2) + 4 * (lane >> 5);
    float v0 = acc0[q] + bv; v0 = v0 > 0.0f ? v0 : 0.0f;
    float v1 = acc1[q] + bv; v1 = v1 > 0.0f ? v1 : 0.0f;
    *(unsigned short*)(outb + lds_addr(row, col * 2)) = f2bf(v0);
    *(unsigned short*)(outb + lds_addr(32 + row, col * 2)) = f2bf(v1);
  }
}

// Small head: wave -> row-group (wave&1), k-quarter (wave>>1): 4 k-tiles of K=256.
template<int NT, int COLS>
__device__ __forceinline__ void small_layer(const uint4* wt, const char* inb,
                                            float* outsm, int wave, int lane) {
  const int rg = wave & 1;
  const int kq = wave >> 1;
  const int arow = rg * 32 + (lane & 31);
  const int khalf = (lane >> 5) * 16;
  U4 b[NT][4];
  #pragma unroll
  for (int n = 0; n < NT; ++n)
    #pragma unroll
    for (int kk = 0; kk < 4; ++kk)
      b[n][kk].u = wt[(size_t)((n * 16 + kq * 4 + kk) * 64 + lane)];
  f32x16 acc[NT];
  #pragma unroll
  for (int n = 0; n < NT; ++n) acc[n] = (f32x16)0.0f;
  #pragma unroll
  for (int kk = 0; kk < 4; ++kk) {
    bf16x8 a = *(const bf16x8*)(inb + lds_addr(arow, (kq * 4 + kk) * 32 + khalf));
    #pragma unroll
    for (int n = 0; n < NT; ++n)
      acc[n] = __builtin_amdgcn_mfma_f32_32x32x16_bf16(a, b[n][kk].h, acc[n], 0, 0, 0);
  }
  #pragma unroll
  for (int n = 0; n < NT; ++n) {
    int col = n * 32 + (lane & 31);
    if (col < COLS) {
      #pragma unroll
      for (int q = 0; q < 16; ++q) {
        int row = rg * 32 + (q & 3) + 8 * (q >> 2) + 4 * (lane >> 5);
        atomicAdd(&outsm[row * COLS + col], acc[n][q]);
      }
    }
  }
}

__global__ void __launch_bounds__(512, 4) deform_main(
    const float* grid_sp, const float* grid_st, const int* idx,
    const float* rays, const float* rotq, const float* shs_in,
    const float* time_emb, const float* h_emb,
    const uint4* ws,
    const float* b_sp, const float* b_st, const float* b_p1, const float* b_p2,
    const float* b_r1, const float* b_r2, const float* b_s1, const float* b_s2,
    const float* b_w1, const float* b_w2, const float* b_m1, const float* b_m2,
    float* out) {
  __shared__ char bufA[32768];
  __shared__ char bufB[32768];
  __shared__ float sm[3456];   // shs/dx [0,3072) | w [3072,3136) | mu [3136,3200) | rot [3200,3456)
  float* dxb  = sm;
  float* shsb = sm;
  float* wb   = sm + 3072;
  float* mub  = sm + 3136;
  float* rotb = sm + 3200;

  const int t = threadIdx.x;
  const int lane = t & 63;
  const int wave = t >> 6;
  const int row0 = blockIdx.x * 64;
  const float tt = time_emb[0];

  // P0: zero small accumulators, stage X_sp
  for (int i = t; i < 576; i += 512) dxb[i] = 0.0f;
  for (int i = 3072 + t; i < 3456; i += 512) sm[i] = 0.0f;
  loadX(grid_sp, row0, t, bufA);
  __syncthreads();
  // P1: hsp
  big_layer<8>(ws + T_SP * 64, b_sp, bufA, bufB, wave, lane);
  __syncthreads();
  // P2: hp
  big_layer<16>(ws + T_P1 * 64, b_p1, bufB, bufA, wave, lane);
  __syncthreads();
  // P3: dx_raw
  small_layer<1, 9>(ws + T_P2 * 64, bufA, dxb, wave, lane);
  __syncthreads();
  // P4: hw
  big_layer<16>(ws + T_W1 * 64, b_w1, bufB, bufA, wave, lane);
  __syncthreads();
  // P5: w_raw
  small_layer<1, 1>(ws + T_W2 * 64, bufA, wb, wave, lane);
  __syncthreads();
  // P6: hm
  big_layer<16>(ws + T_M1 * 64, b_m1, bufB, bufA, wave, lane);
  __syncthreads();
  // P7: mu_raw
  small_layer<1, 1>(ws + T_M2 * 64, bufA, mub, wave, lane);
  __syncthreads();
  // P8: stage X_st + pts/opacity epilogue (thread-parallel, one idx load each)
  loadX(grid_st, row0, t, bufA);
  if (t < 256) {
    int row = t >> 2, sub = t & 3;
    int gr = row0 + row;
    if (gr < M_ROWS) {
      int g = idx[gr];
      if (sub < 3) {
        float mt = 1.0f - tt;
        float c0 = 3.0f * mt * mt * tt, c1 = 3.0f * mt * tt * tt, c2 = tt * tt * tt;
        float d0 = dxb[row * 9 + sub]     + b_p2[sub];
        float d1 = dxb[row * 9 + 3 + sub] + b_p2[3 + sub];
        float d2 = dxb[row * 9 + 6 + sub] + b_p2[6 + sub];
        out[(size_t)g * 3 + sub] = rays[(size_t)g * 3 + sub] + (c0 * d0 + c1 * d1 + c2 * d2);
      } else {
        float wr = wb[row] + b_w2[0];
        float mr = mub[row] + b_m2[0];
        float mu = 1.0f / (1.0f + expf(-mr));
        float dtm = tt - mu;
        out[4200000 + (size_t)g] = h_emb[g] * expf(-(wr * wr) * dtm * dtm);
      }
    }
  }
  __syncthreads();
  // P9: hst
  big_layer<8>(ws + T_ST * 64, b_st, bufA, bufB, wave, lane);
  __syncthreads();
  // P10: hr
  big_layer<16>(ws + T_R1 * 64, b_r1, bufB, bufA, wave, lane);
  __syncthreads();
  // P11: rot_raw + zero shs accumulator (dx region dead)
  for (int i = t; i < 3072; i += 512) shsb[i] = 0.0f;
  small_layer<1, 4>(ws + T_R2 * 64, bufA, rotb, wave, lane);
  __syncthreads();
  // P12: hs + rot epilogue
  big_layer<16>(ws + T_S1 * 64, b_s1, bufB, bufA, wave, lane);
  if (t < 256) {
    int row = t >> 2, c = t & 3;
    int gr = row0 + row;
    if (gr < M_ROWS) {
      int g = idx[gr];
      out[1800000 + (size_t)g * 4 + c] = rotq[(size_t)g * 4 + c] + rotb[row * 4 + c] + b_r2[c];
    }
  }
  __syncthreads();
  // P13: shs_raw
  small_layer<2, 48>(ws + T_S2 * 64, bufA, shsb, wave, lane);
  __syncthreads();
  // P14: shs epilogue (3072 elems / 512 threads)
  #pragma unroll
  for (int i = 0; i < 6; ++i) {
    int e = i * 512 + t;
    int row = e / 48;
    int c = e - row * 48;
    int gr = row0 + row;
    if (gr < M_ROWS) {
      int g = idx[gr];
      out[4800000 + (size_t)g * 48 + c] = shs_in[(size_t)g * 48 + c] + shsb[e] + b_s2[c];
    }
  }
}

extern "C" void kernel_launch(void* const* d_in, const int* in_sizes, int n_in,
                              void* d_out, int out_size, void* d_ws, size_t ws_size,
                              hipStream_t stream) {
  const float* rays     = (const float*)d_in[0];
  const float* rotq     = (const float*)d_in[1];
  const float* shs      = (const float*)d_in[2];
  const float* time_emb = (const float*)d_in[3];
  const float* h_emb    = (const float*)d_in[4];
  const float* grid_sp  = (const float*)d_in[5];
  const float* grid_st  = (const float*)d_in[6];
  const int*   idx      = (const int*)d_in[7];
  uint4* ws = (uint4*)d_ws;

  prep_w<<<T_TOT, 64, 0, stream>>>(
      (const float*)d_in[8],  (const float*)d_in[10], (const float*)d_in[12], (const float*)d_in[14],
      (const float*)d_in[16], (const float*)d_in[18], (const float*)d_in[20], (const float*)d_in[22],
      (const float*)d_in[24], (const float*)d_in[26], (const float*)d_in[28], (const float*)d_in[30],
      ws);

  copy_emb<<<2048, 256, 0, stream>>>((const float4*)rays, (const float4*)rotq,
                                     (const float4*)h_emb, (const float4*)shs, (float4*)d_out);

  deform_main<<<(M_ROWS + 63) / 64, 512, 0, stream>>>(
      grid_sp, grid_st, idx, rays, rotq, shs, time_emb, h_emb, ws,
      (const float*)d_in[9],  (const float*)d_in[11], (const float*)d_in[13], (const float*)d_in[15],
      (const float*)d_in[17], (const float*)d_in[19], (const float*)d_in[21], (const float*)d_in[23],
      (const float*)d_in[25], (const float*)d_in[27], (const float*)d_in[29], (const float*)d_in[31],
      (float*)d_out);
}

// Round 4
// 802.085 us; speedup vs baseline: 1.5124x; 1.1793x over previous
//
#include <hip/hip_runtime.h>
#include <hip/hip_bf16.h>
#include <stdint.h>

#define M_ROWS 300000

typedef __attribute__((ext_vector_type(8)))  short bf16x8;
typedef __attribute__((ext_vector_type(16))) float f32x16;

union U4 { uint4 u; bf16x8 h; unsigned short us[8]; };

__device__ __forceinline__ unsigned short f2bf(float f) {
  union { float f; uint32_t u; } v; v.f = f;
  uint32_t r = v.u + 0x7fffu + ((v.u >> 16) & 1u);
  return (unsigned short)(r >> 16);
}

// ---- packed weight tile table (tiles of 32 cols x 16 k, 1 KiB each) ----
#define T_SP 0
#define T_ST 64
#define T_P1 128
#define T_P2 256
#define T_R1 272
#define T_R2 400
#define T_S1 416
#define T_S2 544
#define T_W1 576
#define T_W2 704
#define T_M1 720
#define T_M2 848
#define T_TOT 864

__global__ void prep_w(const float* Wsp, const float* Wst, const float* Wp1, const float* Wp2,
                       const float* Wr1, const float* Wr2, const float* Ws1, const float* Ws2,
                       const float* Ww1, const float* Ww2, const float* Wm1, const float* Wm2,
                       uint4* ws) {
  int b = blockIdx.x, l = threadIdx.x;
  const int starts[12] = {T_SP,T_ST,T_P1,T_P2,T_R1,T_R2,T_S1,T_S2,T_W1,T_W2,T_M1,T_M2};
  const int Ks[12]     = {128,128,256,256,256,256,256,256,256,256,256,256};
  const int Cos[12]    = {256,256,256,9,256,4,256,48,256,1,256,1};
  const float* Wp[12]  = {Wsp,Wst,Wp1,Wp2,Wr1,Wr2,Ws1,Ws2,Ww1,Ww2,Wm1,Wm2};
  int m = 0;
  #pragma unroll
  for (int i = 1; i < 12; ++i) if (b >= starts[i]) m = i;
  int local = b - starts[m];
  int KT = Ks[m] >> 4;
  int n0 = local / KT, k0 = local - n0 * KT;
  int col = n0 * 32 + (l & 31);
  int kbase = k0 * 16 + (l >> 5) * 8;
  const float* W = Wp[m];
  int Co = Cos[m];
  U4 pk;
  #pragma unroll
  for (int j = 0; j < 8; ++j) {
    float v = (col < Co) ? W[(size_t)(kbase + j) * Co + col] : 0.0f;
    pk.us[j] = f2bf(v);
  }
  ws[(size_t)b * 64 + l] = pk.u;
}

// ---- bulk copy of embeddings into output (non-indexed rows) ----
__global__ void copy_emb(const float4* pts, const float4* rot, const float4* h,
                         const float4* shs, float4* out) {
  long long stride = (long long)gridDim.x * blockDim.x;
  for (long long i = (long long)blockIdx.x * blockDim.x + threadIdx.x; i < 8400000LL; i += stride) {
    float4 v;
    if (i < 450000)        v = pts[i];
    else if (i < 1050000)  v = rot[i - 450000];
    else if (i < 1200000)  v = h[i - 1050000];
    else                   v = shs[i - 1200000];
    out[i] = v;
  }
}

// ---- fused MLP kernel: 64 rows/block, 8 waves, cross-phase weight prefetch ----
#define LSTR 512
__device__ __forceinline__ int lds_addr(int row, int cb) {
  return row * LSTR + (cb ^ ((row & 15) << 4));
}

__device__ __forceinline__ void loadX(const float* grid, int row0, int t, char* buf) {
  #pragma unroll
  for (int i = 0; i < 4; ++i) {
    int fi = i * 512 + t;
    int row = fi >> 5;
    int c4 = fi & 31;
    int gr = row0 + row; gr = gr < M_ROWS ? gr : (M_ROWS - 1);
    float4 v = ((const float4*)grid)[(size_t)gr * 32 + c4];
    ushort4 p;
    p.x = f2bf(v.x); p.y = f2bf(v.y); p.z = f2bf(v.z); p.w = f2bf(v.w);
    *(ushort4*)(buf + lds_addr(row, c4 * 8)) = p;
  }
}

// issue 8 (or 4) weight-tile loads; consumed next sub-phase (latency hidden)
__device__ __forceinline__ void pre8(U4 (&d)[8], const uint4* base, int lane) {
  #pragma unroll
  for (int i = 0; i < 8; ++i) d[i].u = base[(size_t)i * 64 + lane];
}
__device__ __forceinline__ void pre4(U4 (&d)[8], const uint4* base, int lane) {
  #pragma unroll
  for (int i = 0; i < 4; ++i) d[i].u = base[(size_t)i * 64 + lane];
}
__device__ __forceinline__ void pre_s2(U4 (&d)[8], const uint4* wt, int kq, int lane) {
  #pragma unroll
  for (int kk = 0; kk < 4; ++kk)
    #pragma unroll
    for (int n = 0; n < 2; ++n)
      d[kk * 2 + n].u = wt[(size_t)((n * 16 + kq * 4 + kk) * 64) + lane];
}

// 8 k-steps of a big layer (2 row-tiles)
__device__ __forceinline__ void mm_big8(U4 (&b)[8], const char* inb, int k0, int arow, int khalf,
                                        f32x16& acc0, f32x16& acc1) {
  #pragma unroll
  for (int k = 0; k < 8; ++k) {
    bf16x8 a0 = *(const bf16x8*)(inb + lds_addr(arow, (k0 + k) * 32 + khalf));
    bf16x8 a1 = *(const bf16x8*)(inb + lds_addr(32 + arow, (k0 + k) * 32 + khalf));
    acc0 = __builtin_amdgcn_mfma_f32_32x32x16_bf16(a0, b[k].h, acc0, 0, 0, 0);
    acc1 = __builtin_amdgcn_mfma_f32_32x32x16_bf16(a1, b[k].h, acc1, 0, 0, 0);
  }
}

__device__ __forceinline__ void store_act(char* outb, const float* bias, int wave, int lane,
                                          const f32x16& acc0, const f32x16& acc1) {
  const int col = wave * 32 + (lane & 31);
  const float bv = bias[col];
  #pragma unroll
  for (int q = 0; q < 16; ++q) {
    int row = (q & 3) + 8 * (q >> 2) + 4 * (lane >> 5);
    float v0 = acc0[q] + bv; v0 = fmaxf(v0, 0.0f);
    float v1 = acc1[q] + bv; v1 = fmaxf(v1, 0.0f);
    *(unsigned short*)(outb + lds_addr(row, col * 2)) = f2bf(v0);
    *(unsigned short*)(outb + lds_addr(32 + row, col * 2)) = f2bf(v1);
  }
}

// small head, 1 col-tile: wave -> row-group rg, k-quarter kq
__device__ __forceinline__ void mm_head1(U4 (&b)[8], const char* inb, int rg, int kq, int khalf,
                                         int lane, f32x16& acc) {
  const int arow = rg * 32 + (lane & 31);
  #pragma unroll
  for (int kk = 0; kk < 4; ++kk) {
    bf16x8 a = *(const bf16x8*)(inb + lds_addr(arow, (kq * 4 + kk) * 32 + khalf));
    acc = __builtin_amdgcn_mfma_f32_32x32x16_bf16(a, b[kk].h, acc, 0, 0, 0);
  }
}
__device__ __forceinline__ void mm_head2(U4 (&b)[8], const char* inb, int rg, int kq, int khalf,
                                         int lane, f32x16& acc0, f32x16& acc1) {
  const int arow = rg * 32 + (lane & 31);
  #pragma unroll
  for (int kk = 0; kk < 4; ++kk) {
    bf16x8 a = *(const bf16x8*)(inb + lds_addr(arow, (kq * 4 + kk) * 32 + khalf));
    acc0 = __builtin_amdgcn_mfma_f32_32x32x16_bf16(a, b[kk * 2 + 0].h, acc0, 0, 0, 0);
    acc1 = __builtin_amdgcn_mfma_f32_32x32x16_bf16(a, b[kk * 2 + 1].h, acc1, 0, 0, 0);
  }
}

template<int COLS>
__device__ __forceinline__ void head_atomic(float* outsm, int rg, int lane, const f32x16& acc) {
  int col = lane & 31;
  if (col < COLS) {
    #pragma unroll
    for (int q = 0; q < 16; ++q) {
      int row = rg * 32 + (q & 3) + 8 * (q >> 2) + 4 * (lane >> 5);
      atomicAdd(&outsm[row * COLS + col], acc[q]);
    }
  }
}
__device__ __forceinline__ void head_atomic48(float* outsm, int rg, int lane,
                                              const f32x16& a0, const f32x16& a1) {
  int c = lane & 31;
  #pragma unroll
  for (int q = 0; q < 16; ++q) {
    int row = rg * 32 + (q & 3) + 8 * (q >> 2) + 4 * (lane >> 5);
    atomicAdd(&outsm[row * 48 + c], a0[q]);
    if (c < 16) atomicAdd(&outsm[row * 48 + 32 + c], a1[q]);
  }
}

__global__ void __launch_bounds__(512, 4) deform_main(
    const float* grid_sp, const float* grid_st, const int* idx,
    const float* rays, const float* rotq, const float* shs_in,
    const float* time_emb, const float* h_emb,
    const uint4* ws,
    const float* b_sp, const float* b_st, const float* b_p1, const float* b_p2,
    const float* b_r1, const float* b_r2, const float* b_s1, const float* b_s2,
    const float* b_w1, const float* b_w2, const float* b_m1, const float* b_m2,
    float* out) {
  __shared__ char bufA[32768];
  __shared__ char bufB[32768];
  __shared__ float sm[3456];
  float* dxb  = sm;          // [64*9]
  float* shsb = sm;          // [64*48] (aliases dxb, disjoint in time)
  float* wb   = sm + 3072;
  float* mub  = sm + 3136;
  float* rotb = sm + 3200;

  const int t = threadIdx.x;
  const int lane = t & 63;
  const int wave = t >> 6;
  const int rg = wave & 1;
  const int kq = wave >> 1;
  const int arow = lane & 31;
  const int khalf = (lane >> 5) * 16;
  const int row0 = blockIdx.x * 64;
  const float tt = time_emb[0];

  U4 b0[8], b1[8];
  // earliest possible issue of first layer's weights
  pre8(b0, ws + (size_t)(T_SP + wave * 8) * 64, lane);

  // P0: zero small accumulators, stage X_sp
  for (int i = t; i < 576; i += 512) dxb[i] = 0.0f;
  for (int i = 3072 + t; i < 3456; i += 512) sm[i] = 0.0f;
  loadX(grid_sp, row0, t, bufA);
  __syncthreads();

  // L_sp: bufA->bufB (K=128)
  {
    f32x16 a0 = (f32x16)0.0f, a1 = (f32x16)0.0f;
    pre8(b1, ws + (size_t)(T_P1 + wave * 16) * 64, lane);
    mm_big8(b0, bufA, 0, arow, khalf, a0, a1);
    store_act(bufB, b_sp, wave, lane, a0, a1);
  }
  __syncthreads();

  // L_p1: bufB->bufA (K=256, two sub-phases)
  {
    f32x16 a0 = (f32x16)0.0f, a1 = (f32x16)0.0f;
    pre8(b0, ws + (size_t)(T_P1 + wave * 16 + 8) * 64, lane);
    mm_big8(b1, bufB, 0, arow, khalf, a0, a1);
    pre4(b1, ws + (size_t)(T_P2 + kq * 4) * 64, lane);
    mm_big8(b0, bufB, 8, arow, khalf, a0, a1);
    store_act(bufA, b_p1, wave, lane, a0, a1);
  }
  __syncthreads();

  // H_p2: dx head
  {
    f32x16 hacc = (f32x16)0.0f;
    pre8(b0, ws + (size_t)(T_W1 + wave * 16) * 64, lane);
    mm_head1(b1, bufA, rg, kq, khalf, lane, hacc);
    head_atomic<9>(dxb, rg, lane, hacc);
  }
  __syncthreads();

  // L_w1: bufB->bufA
  {
    f32x16 a0 = (f32x16)0.0f, a1 = (f32x16)0.0f;
    pre8(b1, ws + (size_t)(T_W1 + wave * 16 + 8) * 64, lane);
    mm_big8(b0, bufB, 0, arow, khalf, a0, a1);
    pre4(b0, ws + (size_t)(T_W2 + kq * 4) * 64, lane);
    mm_big8(b1, bufB, 8, arow, khalf, a0, a1);
    store_act(bufA, b_w1, wave, lane, a0, a1);
  }
  __syncthreads();

  // H_w2: w head
  {
    f32x16 hacc = (f32x16)0.0f;
    pre8(b1, ws + (size_t)(T_M1 + wave * 16) * 64, lane);
    mm_head1(b0, bufA, rg, kq, khalf, lane, hacc);
    head_atomic<1>(wb, rg, lane, hacc);
  }
  __syncthreads();

  // L_m1: bufB->bufA
  {
    f32x16 a0 = (f32x16)0.0f, a1 = (f32x16)0.0f;
    pre8(b0, ws + (size_t)(T_M1 + wave * 16 + 8) * 64, lane);
    mm_big8(b1, bufB, 0, arow, khalf, a0, a1);
    pre4(b1, ws + (size_t)(T_M2 + kq * 4) * 64, lane);
    mm_big8(b0, bufB, 8, arow, khalf, a0, a1);
    store_act(bufA, b_m1, wave, lane, a0, a1);
  }
  __syncthreads();

  // H_m2: mu head
  {
    f32x16 hacc = (f32x16)0.0f;
    pre8(b0, ws + (size_t)(T_ST + wave * 8) * 64, lane);
    mm_head1(b1, bufA, rg, kq, khalf, lane, hacc);
    head_atomic<1>(mub, rg, lane, hacc);
  }
  __syncthreads();

  // P8: stage X_st + sp-path epilogue
  loadX(grid_st, row0, t, bufA);
  if (t < 256) {
    int row = t >> 2, sub = t & 3;
    int gr = row0 + row;
    if (gr < M_ROWS) {
      int g = idx[gr];
      if (sub < 3) {
        float mt = 1.0f - tt;
        float c0 = 3.0f * mt * mt * tt, c1 = 3.0f * mt * tt * tt, c2 = tt * tt * tt;
        float d0 = dxb[row * 9 + sub]     + b_p2[sub];
        float d1 = dxb[row * 9 + 3 + sub] + b_p2[3 + sub];
        float d2 = dxb[row * 9 + 6 + sub] + b_p2[6 + sub];
        out[(size_t)g * 3 + sub] = rays[(size_t)g * 3 + sub] + (c0 * d0 + c1 * d1 + c2 * d2);
      } else {
        float wr = wb[row] + b_w2[0];
        float mr = mub[row] + b_m2[0];
        float mu = 1.0f / (1.0f + expf(-mr));
        float dtm = tt - mu;
        out[4200000 + (size_t)g] = h_emb[g] * expf(-(wr * wr) * dtm * dtm);
      }
    }
  }
  __syncthreads();

  // L_st: bufA->bufB (K=128)
  {
    f32x16 a0 = (f32x16)0.0f, a1 = (f32x16)0.0f;
    pre8(b1, ws + (size_t)(T_R1 + wave * 16) * 64, lane);
    mm_big8(b0, bufA, 0, arow, khalf, a0, a1);
    store_act(bufB, b_st, wave, lane, a0, a1);
  }
  __syncthreads();

  // L_r1: bufB->bufA
  {
    f32x16 a0 = (f32x16)0.0f, a1 = (f32x16)0.0f;
    pre8(b0, ws + (size_t)(T_R1 + wave * 16 + 8) * 64, lane);
    mm_big8(b1, bufB, 0, arow, khalf, a0, a1);
    pre4(b1, ws + (size_t)(T_R2 + kq * 4) * 64, lane);
    mm_big8(b0, bufB, 8, arow, khalf, a0, a1);
    store_act(bufA, b_r1, wave, lane, a0, a1);
  }
  __syncthreads();

  // H_r2: rot head + zero shs accumulator
  {
    f32x16 hacc = (f32x16)0.0f;
    pre8(b0, ws + (size_t)(T_S1 + wave * 16) * 64, lane);
    mm_head1(b1, bufA, rg, kq, khalf, lane, hacc);
    for (int i = t; i < 3072; i += 512) shsb[i] = 0.0f;
    head_atomic<4>(rotb, rg, lane, hacc);
  }
  __syncthreads();

  // L_s1: bufB->bufA + rot epilogue
  {
    f32x16 a0 = (f32x16)0.0f, a1 = (f32x16)0.0f;
    pre8(b1, ws + (size_t)(T_S1 + wave * 16 + 8) * 64, lane);
    mm_big8(b0, bufB, 0, arow, khalf, a0, a1);
    pre_s2(b0, ws + (size_t)T_S2 * 64, kq, lane);
    mm_big8(b1, bufB, 8, arow, khalf, a0, a1);
    store_act(bufA, b_s1, wave, lane, a0, a1);
    if (t < 256) {
      int row = t >> 2, c = t & 3;
      int gr = row0 + row;
      if (gr < M_ROWS) {
        int g = idx[gr];
        out[1800000 + (size_t)g * 4 + c] = rotq[(size_t)g * 4 + c] + rotb[row * 4 + c] + b_r2[c];
      }
    }
  }
  __syncthreads();

  // H_s2: shs head (2 col-tiles)
  {
    f32x16 h0 = (f32x16)0.0f, h1 = (f32x16)0.0f;
    mm_head2(b0, bufA, rg, kq, khalf, lane, h0, h1);
    head_atomic48(shsb, rg, lane, h0, h1);
  }
  __syncthreads();

  // P14: shs epilogue
  #pragma unroll
  for (int i = 0; i < 6; ++i) {
    int e = i * 512 + t;
    int row = e / 48;
    int c = e - row * 48;
    int gr = row0 + row;
    if (gr < M_ROWS) {
      int g = idx[gr];
      out[4800000 + (size_t)g * 48 + c] = shs_in[(size_t)g * 48 + c] + shsb[e] + b_s2[c];
    }
  }
}

extern "C" void kernel_launch(void* const* d_in, const int* in_sizes, int n_in,
                              void* d_out, int out_size, void* d_ws, size_t ws_size,
                              hipStream_t stream) {
  const float* rays     = (const float*)d_in[0];
  const float* rotq     = (const float*)d_in[1];
  const float* shs      = (const float*)d_in[2];
  const float* time_emb = (const float*)d_in[3];
  const float* h_emb    = (const float*)d_in[4];
  const float* grid_sp  = (const float*)d_in[5];
  const float* grid_st  = (const float*)d_in[6];
  const int*   idx      = (const int*)d_in[7];
  uint4* ws = (uint4*)d_ws;

  prep_w<<<T_TOT, 64, 0, stream>>>(
      (const float*)d_in[8],  (const float*)d_in[10], (const float*)d_in[12], (const float*)d_in[14],
      (const float*)d_in[16], (const float*)d_in[18], (const float*)d_in[20], (const float*)d_in[22],
      (const float*)d_in[24], (const float*)d_in[26], (const float*)d_in[28], (const float*)d_in[30],
      ws);

  copy_emb<<<2048, 256, 0, stream>>>((const float4*)rays, (const float4*)rotq,
                                     (const float4*)h_emb, (const float4*)shs, (float4*)d_out);

  deform_main<<<(M_ROWS + 63) / 64, 512, 0, stream>>>(
      grid_sp, grid_st, idx, rays, rotq, shs, time_emb, h_emb, ws,
      (const float*)d_in[9],  (const float*)d_in[11], (const float*)d_in[13], (const float*)d_in[15],
      (const float*)d_in[17], (const float*)d_in[19], (const float*)d_in[21], (const float*)d_in[23],
      (const float*)d_in[25], (const float*)d_in[27], (const float*)d_in[29], (const float*)d_in[31],
      (float*)d_out);
}